// Round 7
// baseline (322.944 us; speedup 1.0000x reference)
//
#include <hip/hip_runtime.h>
#include <cmath>
#include <cstdint>

#define NB 32
#define NP 24564
#define NC 81
#define NEG_POS 3

static constexpr size_t MINED_ELEMS = (size_t)NB * NP;             // 786,048
static constexpr size_t MINED_BYTES = MINED_ELEMS * sizeof(float); // 3,144,192

// mb_main geometry: one block = one 64-row tile, grid marches contiguously.
#define TILE_ROWS 64
#define TILE_F4   (TILE_ROWS * NC / 4)     // 1296 float4 = 20,736 B
#define NTILES    ((int)(MINED_ELEMS / TILE_ROWS))  // 12282 exact

typedef float f32x4 __attribute__((ext_vector_type(4)));

// ws layout:
//   [0, MINED_BYTES)                    float mined[NB*NP]
//   [MINED_BYTES, +24)                  double acc[3]  {loc_loss, ce_pos_sum, neg_sum}
//   [MINED_BYTES+24, +24+4*NB)          int   num_pos[NB]

__device__ __forceinline__ float wave_reduce_sum(float v) {
#pragma unroll
  for (int off = 32; off > 0; off >>= 1) v += __shfl_down(v, off, 64);
  return v;
}

__device__ __forceinline__ float smooth_l1_4(float4 a, float4 t) {
  float acc = 0.f, d, ax;
  d = a.x - t.x; ax = fabsf(d); acc += (ax < 1.f) ? 0.5f * d * d : ax - 0.5f;
  d = a.y - t.y; ax = fabsf(d); acc += (ax < 1.f) ? 0.5f * d * d : ax - 0.5f;
  d = a.z - t.z; ax = fabsf(d); acc += (ax < 1.f) ? 0.5f * d * d : ax - 0.5f;
  d = a.w - t.w; ax = fabsf(d); acc += (ax < 1.f) ? 0.5f * d * d : ax - 0.5f;
  return acc;
}

__global__ void mb_init(double* __restrict__ acc, int* __restrict__ num_pos) {
  int t = threadIdx.x;
  if (t < 3) acc[t] = 0.0;
  if (t < NB) num_pos[t] = 0;
}

// One block per 64-row tile (rows are flat over [B,P]; CE is row-local, so
// tiles may straddle batch boundaries — num_pos handled by per-positive
// atomics). Block-wide coalesced nontemporal float4 loads -> LDS -> 4 lanes
// per row compute CE. Inter-block overlap (7 blocks/CU) hides HBM latency;
// blocks dispatch in order so the GPU-wide footprint is one marching window.
__global__ __launch_bounds__(256) void mb_main(
    const float* __restrict__ loc_data, const float* __restrict__ conf_data,
    const float* __restrict__ loc_targets, const int* __restrict__ conf_targets,
    float* __restrict__ mined, double* __restrict__ acc, int* __restrict__ num_pos) {
  const int tid = (int)threadIdx.x;
  const int bid = (int)blockIdx.x;          // tile id, 0..12281

  __shared__ float lds[TILE_ROWS * NC];     // 20,736 B
  __shared__ int   lds_tgt[TILE_ROWS];

  // ---- load phase: 1296 float4, nontemporal (stream-once; don't thrash L3) ----
  const f32x4* __restrict__ src4 =
      reinterpret_cast<const f32x4*>(conf_data) + (size_t)bid * TILE_F4;
  f32x4 r[6];
#pragma unroll
  for (int i = 0; i < 5; ++i) r[i] = __builtin_nontemporal_load(src4 + i * 256 + tid);
  if (tid < 16) r[5] = __builtin_nontemporal_load(src4 + 5 * 256 + tid);
  if (tid < TILE_ROWS) lds_tgt[tid] = conf_targets[(size_t)bid * TILE_ROWS + tid];

  f32x4* __restrict__ dst4 = reinterpret_cast<f32x4*>(lds);
#pragma unroll
  for (int i = 0; i < 5; ++i) dst4[i * 256 + tid] = r[i];
  if (tid < 16) dst4[5 * 256 + tid] = r[5];
  __syncthreads();

  // ---- compute: row = tid>>2, part = tid&3 sums classes [20p, 20p+20) ----
  const int row  = tid >> 2;
  const int part = tid & 3;
  const float* __restrict__ rp = lds + row * NC + part * 20;

  float s = 0.f;
#pragma unroll
  for (int j = 0; j < 20; ++j) s += __expf(rp[j]);
  if (part == 3) s += __expf(rp[20]);       // class 80
  s += __shfl_xor(s, 1, 64);
  s += __shfl_xor(s, 2, 64);

  float loc_v = 0.f, ce_pos = 0.f;
  if (part == 0) {
    const int tgt = lds_tgt[row];
    const float tv = lds[row * NC + tgt];
    const float ce = __logf(s) - tv;        // unstabilized LSE safe: |x| < ~6
    const size_t flat = (size_t)bid * TILE_ROWS + row;   // == b*NP + p
    const int is_pos = tgt > 0;
    mined[flat] = is_pos ? 0.f : ce;        // ce > 0 always; bits order as floats
    if (is_pos) {
      ce_pos = ce;
      loc_v = smooth_l1_4(*reinterpret_cast<const float4*>(loc_data + flat * 4),
                          *reinterpret_cast<const float4*>(loc_targets + flat * 4));
      atomicAdd(&num_pos[(int)(flat / NP)], 1);
    }
  }

  // ---- block reduction for the two global sums ----
  __shared__ float red[2][4];
  const int lane = tid & 63;
  const int wid  = tid >> 6;
  float r0 = wave_reduce_sum(loc_v);
  float r1 = wave_reduce_sum(ce_pos);
  if (lane == 0) { red[0][wid] = r0; red[1][wid] = r1; }
  __syncthreads();
  if (tid == 0) {
    float t0 = 0.f, t1 = 0.f;
#pragma unroll
    for (int i = 0; i < 4; ++i) { t0 += red[0][i]; t1 += red[1][i]; }
    if (t0 != 0.f) atomicAdd(&acc[0], (double)t0);
    if (t1 != 0.f) atomicAdd(&acc[1], (double)t1);
  }
}

// One block per batch row: radix-select the (k+1)-th largest of mined[b,:]
// (k = min(3*num_pos, NP-1)), then sum elements strictly greater.
__global__ __launch_bounds__(1024) void mb_select(
    const float* __restrict__ mined, const int* __restrict__ num_pos,
    double* __restrict__ acc) {
  const int b = blockIdx.x;
  const float* __restrict__ row = mined + (size_t)b * NP;
  const int tid = threadIdx.x;
  const int wid = tid >> 6;  // 16 waves

  __shared__ int hist[16][256];   // per-wave histograms (16 KB)
  __shared__ int total[256];
  __shared__ int suffix[256];
  __shared__ unsigned s_prefix;
  __shared__ int s_k;

  if (tid == 0) {
    int k = NEG_POS * num_pos[b];
    if (k > NP - 1) k = NP - 1;
    s_k = k;          // 0-indexed rank, descending order
    s_prefix = 0u;
  }
  __syncthreads();

  for (int shift = 24; shift >= 0; shift -= 8) {
    for (int i = tid; i < 16 * 256; i += 1024) ((int*)hist)[i] = 0;
    __syncthreads();
    const unsigned mask = (shift == 24) ? 0u : (0xFFFFFFFFu << (shift + 8));
    const unsigned pfx = s_prefix;
    const int kcur = s_k;

    for (int q = tid; q < NP / 4; q += 1024) {
      const float4 v = reinterpret_cast<const float4*>(row)[q];
      unsigned u;
      u = __float_as_uint(v.x); if ((u & mask) == pfx) atomicAdd(&hist[wid][(u >> shift) & 255], 1);
      u = __float_as_uint(v.y); if ((u & mask) == pfx) atomicAdd(&hist[wid][(u >> shift) & 255], 1);
      u = __float_as_uint(v.z); if ((u & mask) == pfx) atomicAdd(&hist[wid][(u >> shift) & 255], 1);
      u = __float_as_uint(v.w); if ((u & mask) == pfx) atomicAdd(&hist[wid][(u >> shift) & 255], 1);
    }
    __syncthreads();

    if (tid < 256) {
      int t = 0;
#pragma unroll
      for (int w = 0; w < 16; ++w) t += hist[w][tid];
      total[tid] = t;
      suffix[tid] = t;
    }
    __syncthreads();
    for (int d = 1; d < 256; d <<= 1) {
      int v = 0;
      if (tid < 256) {
        v = suffix[tid];
        if (tid + d < 256) v += suffix[tid + d];
      }
      __syncthreads();
      if (tid < 256) suffix[tid] = v;
      __syncthreads();
    }
    if (tid < 256) {
      const int cs = suffix[tid] - total[tid];   // count strictly above this bin
      if (kcur >= cs && kcur < cs + total[tid]) {
        s_prefix = pfx | ((unsigned)tid << shift);
        s_k = kcur - cs;
      }
    }
    __syncthreads();
  }

  const unsigned vbits = s_prefix;  // exact pivot bit pattern
  float sum = 0.f;
  for (int q = tid; q < NP / 4; q += 1024) {
    const float4 v = reinterpret_cast<const float4*>(row)[q];
    if (__float_as_uint(v.x) > vbits) sum += v.x;
    if (__float_as_uint(v.y) > vbits) sum += v.y;
    if (__float_as_uint(v.z) > vbits) sum += v.z;
    if (__float_as_uint(v.w) > vbits) sum += v.w;
  }

  __shared__ float wsum[16];
  float w = wave_reduce_sum(sum);
  if ((tid & 63) == 0) wsum[tid >> 6] = w;
  __syncthreads();
  if (tid == 0) {
    float t = 0.f;
#pragma unroll
    for (int i = 0; i < 16; ++i) t += wsum[i];
    atomicAdd(&acc[2], (double)t);
  }
}

__global__ void mb_finalize(const double* __restrict__ acc,
                            const int* __restrict__ num_pos,
                            float* __restrict__ out) {
  if (threadIdx.x == 0) {
    int tot = 0;
#pragma unroll
    for (int i = 0; i < NB; ++i) tot += num_pos[i];
    const double n = (double)(tot > 0 ? tot : 1);
    out[0] = (float)((acc[0] + acc[1] + acc[2]) / n);
  }
}

extern "C" void kernel_launch(void* const* d_in, const int* in_sizes, int n_in,
                              void* d_out, int out_size, void* d_ws, size_t ws_size,
                              hipStream_t stream) {
  const float* loc_data     = (const float*)d_in[0];
  const float* conf_data    = (const float*)d_in[1];
  const float* loc_targets  = (const float*)d_in[2];
  const int*   conf_targets = (const int*)d_in[3];
  float* out = (float*)d_out;

  float*  mined   = (float*)d_ws;
  double* acc     = (double*)((char*)d_ws + MINED_BYTES);
  int*    num_pos = (int*)((char*)d_ws + MINED_BYTES + 3 * sizeof(double));

  mb_init<<<1, 64, 0, stream>>>(acc, num_pos);

  mb_main<<<NTILES, 256, 0, stream>>>(loc_data, conf_data, loc_targets,
                                      conf_targets, mined, acc, num_pos);

  mb_select<<<NB, 1024, 0, stream>>>(mined, num_pos, acc);

  mb_finalize<<<1, 64, 0, stream>>>(acc, num_pos, out);
}

// Round 8
// 204.534 us; speedup vs baseline: 1.5789x; 1.5789x over previous
//
#include <hip/hip_runtime.h>
#include <cmath>
#include <cstdint>

#define NB 32
#define NP 24564
#define NC 81
#define NEG_POS 3

static constexpr size_t MINED_ELEMS = (size_t)NB * NP;             // 786,048
static constexpr size_t MINED_BYTES = MINED_ELEMS * sizeof(float); // 3,144,192

#define STRIPS_PER_B (NP / 4)                  // 6141
#define TOTAL_STRIPS (NB * STRIPS_PER_B)       // 196512
#define MAIN_BLOCKS ((TOTAL_STRIPS + 255) / 256)  // 768
#define GROUPS 10                              // 10 groups x 8 float4 + 1 leftover = 81

// ws layout:
//   [0, MINED_BYTES)                    float mined[NB*NP]
//   [MINED_BYTES, +24)                  double acc[3]  {loc_loss, ce_pos_sum, neg_sum}
//   [MINED_BYTES+24, +24+4*NB)          int   num_pos[NB]

__device__ __forceinline__ float wave_reduce_sum(float v) {
#pragma unroll
  for (int off = 32; off > 0; off >>= 1) v += __shfl_down(v, off, 64);
  return v;
}

__device__ __forceinline__ float smooth_l1_4(float4 a, float4 t) {
  float acc = 0.f, d, ax;
  d = a.x - t.x; ax = fabsf(d); acc += (ax < 1.f) ? 0.5f * d * d : ax - 0.5f;
  d = a.y - t.y; ax = fabsf(d); acc += (ax < 1.f) ? 0.5f * d * d : ax - 0.5f;
  d = a.z - t.z; ax = fabsf(d); acc += (ax < 1.f) ? 0.5f * d * d : ax - 0.5f;
  d = a.w - t.w; ax = fabsf(d); acc += (ax < 1.f) ? 0.5f * d * d : ax - 0.5f;
  return acc;
}

__global__ void mb_init(double* __restrict__ acc, int* __restrict__ num_pos) {
  int t = threadIdx.x;
  if (t < 3) acc[t] = 0.0;
  if (t < NB) num_pos[t] = 0;
}

// One thread = one 4-row strip (81 aligned float4). Explicit ping-pong
// register staging (8 float4 per group): consume group g from registers
// while group g+1's loads are in flight. No LDS, no shuffles, no stores,
// no vmcnt(0) drain anywhere in the hot loop -> continuous rolling MLP.
// se[] / mapped row indices are all compile-time after full unroll.
#define CONSUME_Q(v, q)                      \
  do {                                       \
    se[(4 * (q) + 0) / 81] += __expf((v).x); \
    se[(4 * (q) + 1) / 81] += __expf((v).y); \
    se[(4 * (q) + 2) / 81] += __expf((v).z); \
    se[(4 * (q) + 3) / 81] += __expf((v).w); \
  } while (0)

__global__ __launch_bounds__(256, 4) void mb_main(
    const float* __restrict__ loc_data, const float* __restrict__ conf_data,
    const float* __restrict__ loc_targets, const int* __restrict__ conf_targets,
    float* __restrict__ mined, double* __restrict__ acc, int* __restrict__ num_pos) {
  const int s = blockIdx.x * 256 + (int)threadIdx.x;

  float loc_v = 0.f, ce_pos = 0.f;

  if (s < TOTAL_STRIPS) {
    const int b = s / STRIPS_PER_B;
    const int p0 = (s - b * STRIPS_PER_B) * 4;
    const size_t idx = (size_t)b * NP + p0;
    const float* __restrict__ rowp = conf_data + idx * (size_t)NC;
    const float4* __restrict__ src = reinterpret_cast<const float4*>(rowp);

    // upfront: targets, target logits, leftover f4 #80, group 0
    const int4 tg = *reinterpret_cast<const int4*>(conf_targets + idx);
    const float tv0 = rowp[tg.x];
    const float tv1 = rowp[NC + tg.y];
    const float tv2 = rowp[2 * NC + tg.z];
    const float tv3 = rowp[3 * NC + tg.w];
    const float4 last = src[80];

    float4 A[8], B[8];
    float se[4] = {0.f, 0.f, 0.f, 0.f};

#pragma unroll
    for (int i = 0; i < 8; ++i) A[i] = src[i];

#pragma unroll
    for (int g = 0; g < GROUPS; ++g) {
      if ((g & 1) == 0) {
        if (g < GROUPS - 1) {
#pragma unroll
          for (int i = 0; i < 8; ++i) B[i] = src[(g + 1) * 8 + i];
        }
        __builtin_amdgcn_sched_barrier(0);   // keep next-group loads above
#pragma unroll
        for (int i = 0; i < 8; ++i) CONSUME_Q(A[i], g * 8 + i);
      } else {
        if (g < GROUPS - 1) {
#pragma unroll
          for (int i = 0; i < 8; ++i) A[i] = src[(g + 1) * 8 + i];
        }
        __builtin_amdgcn_sched_barrier(0);
#pragma unroll
        for (int i = 0; i < 8; ++i) CONSUME_Q(B[i], g * 8 + i);
      }
    }
    CONSUME_Q(last, 80);   // elements 320..323, all row 3

    // unstabilized logsumexp safe: logits ~ N(0,1), |x| < ~6
    const float ce0 = __logf(se[0]) - tv0;
    const float ce1 = __logf(se[1]) - tv1;
    const float ce2 = __logf(se[2]) - tv2;
    const float ce3 = __logf(se[3]) - tv3;

    const int pos0 = tg.x > 0, pos1 = tg.y > 0, pos2 = tg.z > 0, pos3 = tg.w > 0;

    float4 mo;   // mined: 0 for positives, ce (>0 always) for negatives
    mo.x = pos0 ? 0.f : ce0;
    mo.y = pos1 ? 0.f : ce1;
    mo.z = pos2 ? 0.f : ce2;
    mo.w = pos3 ? 0.f : ce3;
    *reinterpret_cast<float4*>(mined + idx) = mo;

    const int pcnt = pos0 + pos1 + pos2 + pos3;
    if (pcnt) {
      if (pos0) {
        ce_pos += ce0;
        loc_v += smooth_l1_4(*reinterpret_cast<const float4*>(loc_data + idx * 4),
                             *reinterpret_cast<const float4*>(loc_targets + idx * 4));
      }
      if (pos1) {
        ce_pos += ce1;
        loc_v += smooth_l1_4(*reinterpret_cast<const float4*>(loc_data + (idx + 1) * 4),
                             *reinterpret_cast<const float4*>(loc_targets + (idx + 1) * 4));
      }
      if (pos2) {
        ce_pos += ce2;
        loc_v += smooth_l1_4(*reinterpret_cast<const float4*>(loc_data + (idx + 2) * 4),
                             *reinterpret_cast<const float4*>(loc_targets + (idx + 2) * 4));
      }
      if (pos3) {
        ce_pos += ce3;
        loc_v += smooth_l1_4(*reinterpret_cast<const float4*>(loc_data + (idx + 3) * 4),
                             *reinterpret_cast<const float4*>(loc_targets + (idx + 3) * 4));
      }
      atomicAdd(&num_pos[b], pcnt);   // rare (~8% of threads)
    }
  }

  // block reduction for the two global sums
  __shared__ float red[2][4];
  const int lane = threadIdx.x & 63;
  const int wid = threadIdx.x >> 6;
  float r0 = wave_reduce_sum(loc_v);
  float r1 = wave_reduce_sum(ce_pos);
  if (lane == 0) { red[0][wid] = r0; red[1][wid] = r1; }
  __syncthreads();
  if (threadIdx.x == 0) {
    float t0 = 0.f, t1 = 0.f;
#pragma unroll
    for (int i = 0; i < 4; ++i) { t0 += red[0][i]; t1 += red[1][i]; }
    if (t0 != 0.f) atomicAdd(&acc[0], (double)t0);
    if (t1 != 0.f) atomicAdd(&acc[1], (double)t1);
  }
}

// One block per batch row: radix-select the (k+1)-th largest of mined[b,:]
// (k = min(3*num_pos, NP-1)), then sum elements strictly greater.
__global__ __launch_bounds__(1024) void mb_select(
    const float* __restrict__ mined, const int* __restrict__ num_pos,
    double* __restrict__ acc) {
  const int b = blockIdx.x;
  const float* __restrict__ row = mined + (size_t)b * NP;
  const int tid = threadIdx.x;
  const int wid = tid >> 6;  // 16 waves

  __shared__ int hist[16][256];   // per-wave histograms (16 KB)
  __shared__ int total[256];
  __shared__ int suffix[256];
  __shared__ unsigned s_prefix;
  __shared__ int s_k;

  if (tid == 0) {
    int k = NEG_POS * num_pos[b];
    if (k > NP - 1) k = NP - 1;
    s_k = k;          // 0-indexed rank, descending order
    s_prefix = 0u;
  }
  __syncthreads();

  for (int shift = 24; shift >= 0; shift -= 8) {
    for (int i = tid; i < 16 * 256; i += 1024) ((int*)hist)[i] = 0;
    __syncthreads();
    const unsigned mask = (shift == 24) ? 0u : (0xFFFFFFFFu << (shift + 8));
    const unsigned pfx = s_prefix;
    const int kcur = s_k;

    for (int q = tid; q < NP / 4; q += 1024) {
      const float4 v = reinterpret_cast<const float4*>(row)[q];
      unsigned u;
      u = __float_as_uint(v.x); if ((u & mask) == pfx) atomicAdd(&hist[wid][(u >> shift) & 255], 1);
      u = __float_as_uint(v.y); if ((u & mask) == pfx) atomicAdd(&hist[wid][(u >> shift) & 255], 1);
      u = __float_as_uint(v.z); if ((u & mask) == pfx) atomicAdd(&hist[wid][(u >> shift) & 255], 1);
      u = __float_as_uint(v.w); if ((u & mask) == pfx) atomicAdd(&hist[wid][(u >> shift) & 255], 1);
    }
    __syncthreads();

    if (tid < 256) {
      int t = 0;
#pragma unroll
      for (int w = 0; w < 16; ++w) t += hist[w][tid];
      total[tid] = t;
      suffix[tid] = t;
    }
    __syncthreads();
    for (int d = 1; d < 256; d <<= 1) {
      int v = 0;
      if (tid < 256) {
        v = suffix[tid];
        if (tid + d < 256) v += suffix[tid + d];
      }
      __syncthreads();
      if (tid < 256) suffix[tid] = v;
      __syncthreads();
    }
    if (tid < 256) {
      const int cs = suffix[tid] - total[tid];   // count strictly above this bin
      if (kcur >= cs && kcur < cs + total[tid]) {
        s_prefix = pfx | ((unsigned)tid << shift);
        s_k = kcur - cs;
      }
    }
    __syncthreads();
  }

  const unsigned vbits = s_prefix;  // exact pivot bit pattern
  float sum = 0.f;
  for (int q = tid; q < NP / 4; q += 1024) {
    const float4 v = reinterpret_cast<const float4*>(row)[q];
    if (__float_as_uint(v.x) > vbits) sum += v.x;
    if (__float_as_uint(v.y) > vbits) sum += v.y;
    if (__float_as_uint(v.z) > vbits) sum += v.z;
    if (__float_as_uint(v.w) > vbits) sum += v.w;
  }

  __shared__ float wsum[16];
  float w = wave_reduce_sum(sum);
  if ((tid & 63) == 0) wsum[tid >> 6] = w;
  __syncthreads();
  if (tid == 0) {
    float t = 0.f;
#pragma unroll
    for (int i = 0; i < 16; ++i) t += wsum[i];
    atomicAdd(&acc[2], (double)t);
  }
}

__global__ void mb_finalize(const double* __restrict__ acc,
                            const int* __restrict__ num_pos,
                            float* __restrict__ out) {
  if (threadIdx.x == 0) {
    int tot = 0;
#pragma unroll
    for (int i = 0; i < NB; ++i) tot += num_pos[i];
    const double n = (double)(tot > 0 ? tot : 1);
    out[0] = (float)((acc[0] + acc[1] + acc[2]) / n);
  }
}

extern "C" void kernel_launch(void* const* d_in, const int* in_sizes, int n_in,
                              void* d_out, int out_size, void* d_ws, size_t ws_size,
                              hipStream_t stream) {
  const float* loc_data     = (const float*)d_in[0];
  const float* conf_data    = (const float*)d_in[1];
  const float* loc_targets  = (const float*)d_in[2];
  const int*   conf_targets = (const int*)d_in[3];
  float* out = (float*)d_out;

  float*  mined   = (float*)d_ws;
  double* acc     = (double*)((char*)d_ws + MINED_BYTES);
  int*    num_pos = (int*)((char*)d_ws + MINED_BYTES + 3 * sizeof(double));

  mb_init<<<1, 64, 0, stream>>>(acc, num_pos);

  mb_main<<<MAIN_BLOCKS, 256, 0, stream>>>(loc_data, conf_data, loc_targets,
                                           conf_targets, mined, acc, num_pos);

  mb_select<<<NB, 1024, 0, stream>>>(mined, num_pos, acc);

  mb_finalize<<<1, 64, 0, stream>>>(acc, num_pos, out);
}

// Round 9
// 187.259 us; speedup vs baseline: 1.7246x; 1.0923x over previous
//
#include <hip/hip_runtime.h>
#include <cmath>
#include <cstdint>

#define NB 32
#define NP 24564
#define NC 81
#define NEG_POS 3

static constexpr size_t MINED_ELEMS = (size_t)NB * NP;             // 786,048
static constexpr size_t MINED_BYTES = MINED_ELEMS * sizeof(float); // 3,144,192
static constexpr uint32_t CONF_BYTES = (uint32_t)(MINED_ELEMS * NC * 4); // 254,679,552

#define TILE_ROWS 64
#define TILE_BYTES (TILE_ROWS * NC * 4)          // 20,736
#define NTILES ((int)(MINED_ELEMS / TILE_ROWS))  // 12,282 exact
#define TILES_PER_BLOCK 6
#define MAIN_BLOCKS (NTILES / TILES_PER_BLOCK)   // 2,047 exact
#define LDS_FLOATS 6144                          // 24,576 B staged region (>= TILE_BYTES)

// ws layout:
//   [0, MINED_BYTES)                    float mined[NB*NP]
//   [MINED_BYTES, +24)                  double acc[3]  {loc_loss, ce_pos_sum, neg_sum}
//   [MINED_BYTES+24, +24+4*NB)          int   num_pos[NB]

__device__ __forceinline__ float wave_reduce_sum(float v) {
#pragma unroll
  for (int off = 32; off > 0; off >>= 1) v += __shfl_down(v, off, 64);
  return v;
}

__device__ __forceinline__ float smooth_l1_4(float4 a, float4 t) {
  float acc = 0.f, d, ax;
  d = a.x - t.x; ax = fabsf(d); acc += (ax < 1.f) ? 0.5f * d * d : ax - 0.5f;
  d = a.y - t.y; ax = fabsf(d); acc += (ax < 1.f) ? 0.5f * d * d : ax - 0.5f;
  d = a.z - t.z; ax = fabsf(d); acc += (ax < 1.f) ? 0.5f * d * d : ax - 0.5f;
  d = a.w - t.w; ax = fabsf(d); acc += (ax < 1.f) ? 0.5f * d * d : ax - 0.5f;
  return acc;
}

__global__ void mb_init(double* __restrict__ acc, int* __restrict__ num_pos) {
  int t = threadIdx.x;
  if (t < 3) acc[t] = 0.0;
  if (t < NB) num_pos[t] = 0;
}

// Async stage one 64-row tile (20,736 B; issues 24,576 B, tail clamped) into
// LDS via global_load_lds width=16. Fire-and-forget: no VGPR round trip, the
// only wait is the explicit vmcnt(0) at phase end. Wave w stages bytes
// [w*6144, (w+1)*6144) of the tile; LDS dest is wave-uniform base + lane*16.
__device__ __forceinline__ void stage_tile(const char* __restrict__ conf_base,
                                           uint32_t tile, float* buf,
                                           int wid, int lane) {
  const uint32_t SAFE = CONF_BYTES - 16;
  uint32_t off0 = tile * (uint32_t)TILE_BYTES + (uint32_t)(wid * 6144 + lane * 16);
#pragma unroll
  for (int i = 0; i < 6; ++i) {
    uint32_t off = off0 + (uint32_t)(i * 1024);
    off = (off <= SAFE) ? off : SAFE;            // per-lane clamp (last tile only)
    const void* g = conf_base + off;
    float* l = buf + wid * 1536 + i * 256;       // wave-uniform LDS base
    __builtin_amdgcn_global_load_lds(
        (const __attribute__((address_space(1))) void*)g,
        (__attribute__((address_space(3))) void*)l, 16, 0, 0);
  }
}

// Compute one tile from LDS: row = tid>>2 owns a row with 4 lanes; part p
// sums classes [20p, 20p+20) (+ class 80 on part 3); quad shfl_xor reduce.
__device__ __forceinline__ void compute_tile(
    const float* __restrict__ L, int tile, int tgt, int row, int part,
    const float* __restrict__ loc_data, const float* __restrict__ loc_targets,
    float* __restrict__ mined, int* __restrict__ num_pos,
    float& loc_v, float& ce_pos) {
  const float* rp = L + row * NC + part * 20;
  float s = 0.f;
#pragma unroll
  for (int j = 0; j < 20; ++j) s += __expf(rp[j]);
  if (part == 3) s += __expf(L[row * NC + 80]);
  s += __shfl_xor(s, 1, 64);
  s += __shfl_xor(s, 2, 64);
  if (part == 0) {
    const float tv = L[row * NC + tgt];
    const float ce = __logf(s) - tv;             // unstabilized LSE safe: |x| < ~6
    const size_t flat = (size_t)tile * TILE_ROWS + row;
    const int is_pos = tgt > 0;
    mined[flat] = is_pos ? 0.f : ce;             // ce > 0; bits order as floats
    if (is_pos) {
      ce_pos += ce;
      loc_v += smooth_l1_4(*reinterpret_cast<const float4*>(loc_data + flat * 4),
                           *reinterpret_cast<const float4*>(loc_targets + flat * 4));
      atomicAdd(&num_pos[(int)(flat / NP)], 1);
    }
  }
}

#define DRAIN_BARRIER()                                \
  do {                                                 \
    asm volatile("s_waitcnt vmcnt(0)" ::: "memory");   \
    __builtin_amdgcn_s_barrier();                      \
  } while (0)

__global__ __launch_bounds__(256) void mb_main(
    const float* __restrict__ loc_data, const float* __restrict__ conf_data,
    const float* __restrict__ loc_targets, const int* __restrict__ conf_targets,
    float* __restrict__ mined, double* __restrict__ acc, int* __restrict__ num_pos) {
  __shared__ float ldsA[LDS_FLOATS];   // two separate symbols: compile-time
  __shared__ float ldsB[LDS_FLOATS];   // buffer selection, clean aliasing

  const int tid = (int)threadIdx.x;
  const int wid = tid >> 6, lane = tid & 63;
  const int row = tid >> 2, part = tid & 3;
  const int t0 = (int)blockIdx.x * TILES_PER_BLOCK;
  const char* cbase = (const char*)conf_data;

  float loc_v = 0.f, ce_pos = 0.f;

  // prologue: stage tile t0 into A
  stage_tile(cbase, (uint32_t)t0, ldsA, wid, lane);
  int tgtA = conf_targets[(size_t)t0 * TILE_ROWS + row];
  int tgtB = 0;
  DRAIN_BARRIER();

#pragma unroll
  for (int u = 0; u < 3; ++u) {
    const int tA = t0 + 2 * u;

    // phase 1: stage B(tA+1) || compute A(tA)
    stage_tile(cbase, (uint32_t)(tA + 1), ldsB, wid, lane);
    tgtB = conf_targets[(size_t)(tA + 1) * TILE_ROWS + row];
    compute_tile(ldsA, tA, tgtA, row, part, loc_data, loc_targets,
                 mined, num_pos, loc_v, ce_pos);
    DRAIN_BARRIER();

    // phase 2: stage A(tA+2) || compute B(tA+1)
    if (u < 2) {
      stage_tile(cbase, (uint32_t)(tA + 2), ldsA, wid, lane);
      tgtA = conf_targets[(size_t)(tA + 2) * TILE_ROWS + row];
    }
    compute_tile(ldsB, tA + 1, tgtB, row, part, loc_data, loc_targets,
                 mined, num_pos, loc_v, ce_pos);
    if (u < 2) DRAIN_BARRIER();
  }

  // block reduction for the two global sums
  __shared__ float red[2][4];
  float r0 = wave_reduce_sum(loc_v);
  float r1 = wave_reduce_sum(ce_pos);
  if (lane == 0) { red[0][wid] = r0; red[1][wid] = r1; }
  __syncthreads();
  if (tid == 0) {
    float s0 = 0.f, s1 = 0.f;
#pragma unroll
    for (int i = 0; i < 4; ++i) { s0 += red[0][i]; s1 += red[1][i]; }
    if (s0 != 0.f) atomicAdd(&acc[0], (double)s0);
    if (s1 != 0.f) atomicAdd(&acc[1], (double)s1);
  }
}

// One block per batch row: radix-select the (k+1)-th largest of mined[b,:]
// (k = min(3*num_pos, NP-1)), then sum elements strictly greater.
__global__ __launch_bounds__(1024) void mb_select(
    const float* __restrict__ mined, const int* __restrict__ num_pos,
    double* __restrict__ acc) {
  const int b = blockIdx.x;
  const float* __restrict__ row = mined + (size_t)b * NP;
  const int tid = threadIdx.x;
  const int wid = tid >> 6;  // 16 waves

  __shared__ int hist[16][256];   // per-wave histograms (16 KB)
  __shared__ int total[256];
  __shared__ int suffix[256];
  __shared__ unsigned s_prefix;
  __shared__ int s_k;

  if (tid == 0) {
    int k = NEG_POS * num_pos[b];
    if (k > NP - 1) k = NP - 1;
    s_k = k;          // 0-indexed rank, descending order
    s_prefix = 0u;
  }
  __syncthreads();

  for (int shift = 24; shift >= 0; shift -= 8) {
    for (int i = tid; i < 16 * 256; i += 1024) ((int*)hist)[i] = 0;
    __syncthreads();
    const unsigned mask = (shift == 24) ? 0u : (0xFFFFFFFFu << (shift + 8));
    const unsigned pfx = s_prefix;
    const int kcur = s_k;

    for (int q = tid; q < NP / 4; q += 1024) {
      const float4 v = reinterpret_cast<const float4*>(row)[q];
      unsigned u;
      u = __float_as_uint(v.x); if ((u & mask) == pfx) atomicAdd(&hist[wid][(u >> shift) & 255], 1);
      u = __float_as_uint(v.y); if ((u & mask) == pfx) atomicAdd(&hist[wid][(u >> shift) & 255], 1);
      u = __float_as_uint(v.z); if ((u & mask) == pfx) atomicAdd(&hist[wid][(u >> shift) & 255], 1);
      u = __float_as_uint(v.w); if ((u & mask) == pfx) atomicAdd(&hist[wid][(u >> shift) & 255], 1);
    }
    __syncthreads();

    if (tid < 256) {
      int t = 0;
#pragma unroll
      for (int w = 0; w < 16; ++w) t += hist[w][tid];
      total[tid] = t;
      suffix[tid] = t;
    }
    __syncthreads();
    for (int d = 1; d < 256; d <<= 1) {
      int v = 0;
      if (tid < 256) {
        v = suffix[tid];
        if (tid + d < 256) v += suffix[tid + d];
      }
      __syncthreads();
      if (tid < 256) suffix[tid] = v;
      __syncthreads();
    }
    if (tid < 256) {
      const int cs = suffix[tid] - total[tid];   // count strictly above this bin
      if (kcur >= cs && kcur < cs + total[tid]) {
        s_prefix = pfx | ((unsigned)tid << shift);
        s_k = kcur - cs;
      }
    }
    __syncthreads();
  }

  const unsigned vbits = s_prefix;  // exact pivot bit pattern
  float sum = 0.f;
  for (int q = tid; q < NP / 4; q += 1024) {
    const float4 v = reinterpret_cast<const float4*>(row)[q];
    if (__float_as_uint(v.x) > vbits) sum += v.x;
    if (__float_as_uint(v.y) > vbits) sum += v.y;
    if (__float_as_uint(v.z) > vbits) sum += v.z;
    if (__float_as_uint(v.w) > vbits) sum += v.w;
  }

  __shared__ float wsum[16];
  float w = wave_reduce_sum(sum);
  if ((tid & 63) == 0) wsum[tid >> 6] = w;
  __syncthreads();
  if (tid == 0) {
    float t = 0.f;
#pragma unroll
    for (int i = 0; i < 16; ++i) t += wsum[i];
    atomicAdd(&acc[2], (double)t);
  }
}

__global__ void mb_finalize(const double* __restrict__ acc,
                            const int* __restrict__ num_pos,
                            float* __restrict__ out) {
  if (threadIdx.x == 0) {
    int tot = 0;
#pragma unroll
    for (int i = 0; i < NB; ++i) tot += num_pos[i];
    const double n = (double)(tot > 0 ? tot : 1);
    out[0] = (float)((acc[0] + acc[1] + acc[2]) / n);
  }
}

extern "C" void kernel_launch(void* const* d_in, const int* in_sizes, int n_in,
                              void* d_out, int out_size, void* d_ws, size_t ws_size,
                              hipStream_t stream) {
  const float* loc_data     = (const float*)d_in[0];
  const float* conf_data    = (const float*)d_in[1];
  const float* loc_targets  = (const float*)d_in[2];
  const int*   conf_targets = (const int*)d_in[3];
  float* out = (float*)d_out;

  float*  mined   = (float*)d_ws;
  double* acc     = (double*)((char*)d_ws + MINED_BYTES);
  int*    num_pos = (int*)((char*)d_ws + MINED_BYTES + 3 * sizeof(double));

  mb_init<<<1, 64, 0, stream>>>(acc, num_pos);

  mb_main<<<MAIN_BLOCKS, 256, 0, stream>>>(loc_data, conf_data, loc_targets,
                                           conf_targets, mined, acc, num_pos);

  mb_select<<<NB, 1024, 0, stream>>>(mined, num_pos, acc);

  mb_finalize<<<1, 64, 0, stream>>>(acc, num_pos, out);
}